// Round 1
// baseline (329.808 us; speedup 1.0000x reference)
//
#include <hip/hip_runtime.h>

typedef float f2 __attribute__((ext_vector_type(2)));

constexpr int Tt = 512;    // sequence length
constexpr int Bb = 256;    // batch
constexpr int Ee = 200;    // word-embedding dim
constexpr int Gg = 96;     // 4*H
constexpr int Vv = 50000;  // vocab

__device__ __forceinline__ float fast_rcp(float x) { return __builtin_amdgcn_rcpf(x); }
__device__ __forceinline__ float sigf(float x) { return fast_rcp(1.f + __expf(-x)); }
// tanh via exp(2x); saturates correctly for |x| large (inf -> 1, 0 -> -1)
__device__ __forceinline__ float tanhf_(float x) {
    float e = __expf(2.f * x);
    return 1.f - 2.f * fast_rcp(e + 1.f);
}

// ---------------------------------------------------------------------------
// Kernel A: EwW[w][j*4+c] = sum_k Ew[w][k] * Wl[k][c*24+j]   (gate-interleaved)
// GEMM 50000 x 200 x 96, fp32, BM=32 BN=96 BK=8, thread tile TM=2 x TN=6.
// ---------------------------------------------------------------------------
__global__ __launch_bounds__(256) void ew_proj(const float* __restrict__ Ew,
                                               const float* __restrict__ Wl,
                                               float* __restrict__ EwW)
{
    constexpr int BM = 32, BK = 8;
    __shared__ float As[BK][BM];
    __shared__ float Bs[BK][Gg];
    const int tid = threadIdx.x;
    const int w0  = blockIdx.x * BM;
    const int tc  = tid & 15;   // 16 col groups * TN=6 -> 96
    const int tr  = tid >> 4;   // 16 row groups * TM=2 -> 32
    float acc0[6] = {0.f, 0.f, 0.f, 0.f, 0.f, 0.f};
    float acc1[6] = {0.f, 0.f, 0.f, 0.f, 0.f, 0.f};

    for (int k0 = 0; k0 < Ee; k0 += BK) {
        // stage A tile (32 words x 8 k), transposed [k][m]
        {
            const int kk = tid & 7;
            const int m  = tid >> 3;
            const int w  = w0 + m;
            As[kk][m] = (w < Vv) ? Ew[w * Ee + k0 + kk] : 0.f;
        }
        // stage B tile (8 k x 96), permuted to gate-interleaved column order
        {
            const int kk = tid >> 5;          // 0..7
            const int gb = (tid & 31) * 3;    // 0..93
            #pragma unroll
            for (int u = 0; u < 3; ++u) {
                const int g  = gb + u;
                const int gp = (g % 24) * 4 + (g / 24);
                Bs[kk][gp] = Wl[(k0 + kk) * Gg + g];
            }
        }
        __syncthreads();
        #pragma unroll
        for (int kk = 0; kk < BK; ++kk) {
            const float a0 = As[kk][tr * 2 + 0];
            const float a1 = As[kk][tr * 2 + 1];
            float bb[6];
            #pragma unroll
            for (int u = 0; u < 6; ++u) bb[u] = Bs[kk][tc * 6 + u];
            #pragma unroll
            for (int u = 0; u < 6; ++u) {
                acc0[u] += a0 * bb[u];
                acc1[u] += a1 * bb[u];
            }
        }
        __syncthreads();
    }
    const int wa = w0 + tr * 2;
    if (wa < Vv) {
        #pragma unroll
        for (int u = 0; u < 6; ++u) EwW[wa * Gg + tc * 6 + u] = acc0[u];
    }
    if (wa + 1 < Vv) {
        #pragma unroll
        for (int u = 0; u < 6; ++u) EwW[(wa + 1) * Gg + tc * 6 + u] = acc1[u];
    }
}

// ---------------------------------------------------------------------------
// Kernel C: sequential LSTM + mean-pool + MLP head.
// 1 wave per block; 2 batch elements per wave (lanes 0-23 / 32-55 active).
// Lane j owns hidden unit j: holds U columns (i,j,f,o) in registers,
// computes gates locally -> no cross-lane traffic except h broadcast via LDS.
// ---------------------------------------------------------------------------
__global__ __launch_bounds__(64, 1) void lstm_head(
    const int* __restrict__ words, const int* __restrict__ caps,
    const float* __restrict__ Ec,  const float* __restrict__ Wl,
    const float* __restrict__ bl,  const float* __restrict__ EwW,
    const float* __restrict__ W1,  const float* __restrict__ b1,
    const float* __restrict__ W2,  const float* __restrict__ b2,
    float* __restrict__ out)
{
    __shared__ float4 EcB[3][24];     // cap -> per-unit (i,j,f,o) incl. b_lstm
    __shared__ float4 hbuf4[2][6];    // h per batch-half, 24 floats each
    __shared__ float  a1buf[2][50];

    const int  lane = threadIdx.x;
    const int  half = lane >> 5;
    const int  j    = lane & 31;
    const int  jc   = (j < 24) ? j : 23;  // clamp for safe (ignored) loads
    const bool act  = (j < 24);
    const int  b    = blockIdx.x * 2 + half;

    // EcB[cap][unit] = Ec[cap] @ Wl[200:203] + b_lstm   (gate-interleaved)
    for (int e = lane; e < 72; e += 64) {
        const int cap = e / 24, jj = e % 24;
        float4 v;
        #pragma unroll
        for (int c = 0; c < 4; ++c) {
            float s = bl[c * 24 + jj];
            #pragma unroll
            for (int kk = 0; kk < 3; ++kk)
                s += Ec[cap * 3 + kk] * Wl[(200 + kk) * Gg + c * 24 + jj];
            (&v.x)[c] = s;
        }
        EcB[cap][jj] = v;
    }
    if (act) ((float*)hbuf4)[half * 24 + jc] = 0.f;
    __syncthreads();

    // preload recurrent weights: lane j's 4 U-columns (96 VGPRs)
    f2 uij[24], ufo[24];
    #pragma unroll
    for (int k = 0; k < 24; ++k) {
        const int base = (203 + k) * Gg;
        f2 a, o2;
        a.x  = Wl[base + 0  + jc];
        a.y  = Wl[base + 24 + jc];
        o2.x = Wl[base + 48 + jc];
        o2.y = Wl[base + 72 + jc];
        uij[k] = a;
        ufo[k] = o2;
    }

    const int* wrow = words + b * Tt;
    const int* crow = caps  + b * Tt;
    const int  off  = jc * 4;

    // software pipeline: x for t ready; x for t+1 in flight; idx for t+2 held
    int wi2 = wrow[2];
    int cp0 = crow[0], cp1 = crow[1], cp2 = crow[2];
    float4 x0 = *(const float4*)(EwW + (long)wrow[0] * Gg + off);
    float4 x1 = *(const float4*)(EwW + (long)wrow[1] * Gg + off);

    float cstate = 0.f, hsum = 0.f;

    for (int t = 0; t < Tt; ++t) {
        // issue gather for t+2 and index load for t+3
        const float4 x2 = *(const float4*)(EwW + (long)wi2 * Gg + off);
        const int tn  = (t + 3 < Tt) ? (t + 3) : (Tt - 1);
        const int wi3 = wrow[tn];
        const int cp3 = crow[tn];

        const float4 ecb = EcB[cp0][jc];
        f2 zij, zfo;
        zij.x = x0.x + ecb.x;  zij.y = x0.y + ecb.y;
        zfo.x = x0.z + ecb.z;  zfo.y = x0.w + ecb.w;

        // broadcast h (24 floats, 6x ds_read_b128, same addr -> no conflicts)
        float4 hv[6];
        #pragma unroll
        for (int q = 0; q < 6; ++q) hv[q] = hbuf4[half][q];

        #pragma unroll
        for (int k = 0; k < 24; ++k) {
            const float hk = (&hv[k >> 2].x)[k & 3];
            f2 hk2; hk2.x = hk; hk2.y = hk;
            zij += hk2 * uij[k];   // -> v_pk_fma_f32
            zfo += hk2 * ufo[k];
        }

        const float ig = sigf(zij.x);
        const float tj = tanhf_(zij.y);
        const float fg = sigf(zfo.x + 1.0f);   // forget bias
        const float og = sigf(zfo.y);
        cstate = fg * cstate + ig * tj;
        const float hn = og * tanhf_(cstate);
        hsum += hn;
        if (act) ((float*)hbuf4)[half * 24 + jc] = hn;
        __syncthreads();   // 1-wave workgroup: effectively just lgkm drain

        x0 = x1; x1 = x2;
        wi2 = wi3;
        cp0 = cp1; cp1 = cp2; cp2 = cp3;
    }

    // ---- epilogue: mean-pool + MLP head -----------------------------------
    if (act) ((float*)hbuf4)[half * 24 + jc] = hsum * (1.f / (float)Tt);
    __syncthreads();

    float4 mv[6];
    #pragma unroll
    for (int q = 0; q < 6; ++q) mv[q] = hbuf4[half][q];

    if (j < 25) {
        #pragma unroll
        for (int p = 0; p < 2; ++p) {
            const int q = j + p * 25;
            float s = b1[q];
            #pragma unroll
            for (int k = 0; k < 24; ++k)
                s += (&mv[k >> 2].x)[k & 3] * W1[k * 50 + q];
            a1buf[half][q] = (s > 0.f) ? s : (__expf(s) - 1.f);  // ELU
        }
    }
    __syncthreads();

    if (j < 6) {
        float s = b2[j];
        for (int q = 0; q < 50; ++q) s += a1buf[half][q] * W2[q * 6 + j];
        out[b * 6 + j] = sigf(s);
    }
}

// ---------------------------------------------------------------------------
extern "C" void kernel_launch(void* const* d_in, const int* in_sizes, int n_in,
                              void* d_out, int out_size, void* d_ws, size_t ws_size,
                              hipStream_t stream)
{
    const int*   words = (const int*)d_in[0];
    const int*   caps  = (const int*)d_in[1];
    const float* Ew    = (const float*)d_in[2];
    const float* Ec    = (const float*)d_in[3];
    const float* Wl    = (const float*)d_in[4];
    const float* bl    = (const float*)d_in[5];
    const float* W1    = (const float*)d_in[6];
    const float* b1    = (const float*)d_in[7];
    const float* W2    = (const float*)d_in[8];
    const float* b2    = (const float*)d_in[9];
    float* out = (float*)d_out;
    float* EwW = (float*)d_ws;   // 50000 * 96 floats = 19.2 MB scratch

    ew_proj<<<(Vv + 31) / 32, 256, 0, stream>>>(Ew, Wl, EwW);
    lstm_head<<<Bb / 2, 64, 0, stream>>>(words, caps, Ec, Wl, bl, EwW,
                                         W1, b1, W2, b2, out);
}